// Round 6
// baseline (176.941 us; speedup 1.0000x reference)
//
#include <hip/hip_runtime.h>

#define S_LEN 2048
#define D_DIM 1024
#define NH 16
#define HD 64
#define BATCH 2

// 0.125 (1/sqrt(hd)) * log2(e): folded into Wq/bq so QK^T scores are base-2
#define QK_SCALE 0.18033688011112042f
#define LOG2E 1.4426950408889634f

using s16x8 = __attribute__((ext_vector_type(8))) short;
using u16x8 = __attribute__((ext_vector_type(8))) unsigned short;
using f32x4 = __attribute__((ext_vector_type(4))) float;
using bf16x8v = __attribute__((ext_vector_type(8))) __bf16;

typedef const __attribute__((address_space(1))) unsigned int* gas_ptr;
typedef __attribute__((address_space(3))) unsigned int* las_ptr;

__device__ __forceinline__ unsigned short f32_to_bf16(float f) {
  unsigned int u = __float_as_uint(f);
  u += 0x7FFFu + ((u >> 16) & 1u);
  return (unsigned short)(u >> 16);
}

__device__ __forceinline__ f32x4 mfma_bf16(s16x8 a, s16x8 b, f32x4 c) {
  return __builtin_amdgcn_mfma_f32_16x16x32_bf16(
      __builtin_bit_cast(bf16x8v, a), __builtin_bit_cast(bf16x8v, b), c, 0, 0, 0);
}

// v_exp_f32 computes 2^x natively (ISA §3)
__device__ __forceinline__ float exp2_fast(float x) {
  float r;
  asm("v_exp_f32 %0, %1" : "=v"(r) : "v"(x));
  return r;
}

// ---------------- conversion kernels ----------------

__global__ __launch_bounds__(256) void cvt_hs_bf16(const float* __restrict__ in,
                                                   unsigned short* __restrict__ out) {
  int i = (blockIdx.x * 256 + threadIdx.x) * 8;
  float4 v0 = *(const float4*)(in + i);
  float4 v1 = *(const float4*)(in + i + 4);
  u16x8 o;
  o[0] = f32_to_bf16(v0.x); o[1] = f32_to_bf16(v0.y);
  o[2] = f32_to_bf16(v0.z); o[3] = f32_to_bf16(v0.w);
  o[4] = f32_to_bf16(v1.x); o[5] = f32_to_bf16(v1.y);
  o[6] = f32_to_bf16(v1.z); o[7] = f32_to_bf16(v1.w);
  *(u16x8*)(out + i) = o;
}

// WT[n][k] = W[k][n] * scale, f32 -> bf16
__global__ __launch_bounds__(256) void transpose_w(const float* __restrict__ W,
                                                   unsigned short* __restrict__ WT,
                                                   float scale) {
  __shared__ float tile[32][33];
  int tx = threadIdx.x & 31;
  int ty = threadIdx.x >> 5;  // 0..7
  int c0 = blockIdx.x * 32;   // n range
  int r0 = blockIdx.y * 32;   // k range
#pragma unroll
  for (int i = 0; i < 4; ++i)
    tile[ty + i * 8][tx] = W[(r0 + ty + i * 8) * D_DIM + c0 + tx];
  __syncthreads();
#pragma unroll
  for (int i = 0; i < 4; ++i)
    WT[(c0 + ty + i * 8) * D_DIM + r0 + tx] = f32_to_bf16(tile[tx][ty + i * 8] * scale);
}

// ---------------- pooling + gate ----------------

__global__ __launch_bounds__(256) void pool_partial(const float* __restrict__ hs,
                                                    float* __restrict__ partial) {
  int bid = blockIdx.x;  // 64 = 2 * 8 * 4
  int b = bid & 1;
  int chunk = (bid >> 1) & 7;
  int dq = bid >> 4;  // 0..3
  int d = dq * 256 + threadIdx.x;
  const float* p = hs + ((size_t)b * S_LEN + chunk * 256) * D_DIM + d;
  float s = 0.f;
  for (int i = 0; i < 256; ++i) s += p[(size_t)i * D_DIM];
  partial[(b * 8 + chunk) * D_DIM + d] = s;
}

__global__ __launch_bounds__(256) void gate_kernel(
    const float* __restrict__ partial, const float* __restrict__ pW1,
    const float* __restrict__ pb1, const float* __restrict__ gamma,
    const float* __restrict__ beta, const float* __restrict__ mean,
    const float* __restrict__ var, const float* __restrict__ pW2,
    const float* __restrict__ pb2, float* __restrict__ gate) {
  __shared__ float pooled[2 * D_DIM];
  __shared__ float hsh[2][64];
  int t = threadIdx.x;
  for (int idx = t; idx < 2 * D_DIM; idx += 256) {
    int b = idx >> 10, k = idx & 1023;
    float s = 0.f;
#pragma unroll
    for (int c = 0; c < 8; ++c) s += partial[(b * 8 + c) * D_DIM + k];
    pooled[idx] = s * (1.0f / 2048.0f);
  }
  __syncthreads();
  // 2 threads per (b,j): split k-range, shfl combine
  int b = t >> 7, jj = (t >> 1) & 63, half = t & 1;
  float acc = 0.f;
  for (int k = half * 512; k < half * 512 + 512; ++k)
    acc += pooled[b * D_DIM + k] * pW1[k * 64 + jj];
  acc += __shfl_xor(acc, 1, 64);
  if (half == 0) {
    acc += pb1[jj];
    acc = (acc - mean[jj]) * rsqrtf(var[jj] + 1e-12f) * gamma[jj] + beta[jj];
    hsh[b][jj] = fmaxf(acc, 0.f);
  }
  __syncthreads();
  if (t < 32) {
    int bb = t >> 4, hh = t & 15;
    float lg = pb2[hh];
#pragma unroll
    for (int kk = 0; kk < 64; ++kk) lg += hsh[bb][kk] * pW2[kk * NH + hh];
    gate[bb * NH + hh] = (lg >= 0.f) ? 1.f : 0.f;
  }
}

// ---------------- projection GEMM (m97 structure: global_load_lds staging) -------
// C[m][n] = sum_k A[m][k]*BT[n][k] + bias. 128x128 tile, BK=32, 4 waves (2x2 of
// 64x64), 16 MFMA/iter, 16B global_load_lds staging, linear LDS.
// mode 0 (fused QK): A=hs_bf16 (M=4096), BT=wTq||wTk (N=2048);
//   col<1024 -> Q (bias0*QK_SCALE, out0), else K (bias1, out1); out [b,h,s,d].
// mode 1 (V^T): A=wTv (M=1024), BT=hs_bf16 (N=4096); out [b,h,d,s] bf16.
__global__ __launch_bounds__(256) void proj_gemm2(
    const unsigned short* __restrict__ A, const unsigned short* __restrict__ BT,
    const float* __restrict__ bias0, const float* __restrict__ bias1,
    unsigned short* __restrict__ out0, unsigned short* __restrict__ out1,
    int mode) {
  __shared__ __align__(16) unsigned short As[128 * 32];
  __shared__ __align__(16) unsigned short Bs[128 * 32];
  int m0 = blockIdx.x * 128, n0 = blockIdx.y * 128;
  int tid = threadIdx.x, wave = tid >> 6, lane = tid & 63;
  int l15 = lane & 15, lhi = lane >> 4;
  int wm = (wave >> 1) * 64, wn = (wave & 1) * 64;
  int srow = tid >> 2;        // 0..63: row within the 64-row half per round
  int scol = (tid & 3) * 8;   // element col 0/8/16/24
  f32x4 acc[4][4] = {};

  for (int k0 = 0; k0 < D_DIM; k0 += 32) {
#pragma unroll
    for (int j = 0; j < 2; ++j) {
      __builtin_amdgcn_global_load_lds(
          (gas_ptr)(A + (size_t)(m0 + j * 64 + srow) * D_DIM + k0 + scol),
          (las_ptr)((char*)As + j * 4096 + wave * 1024), 16, 0, 0);
      __builtin_amdgcn_global_load_lds(
          (gas_ptr)(BT + (size_t)(n0 + j * 64 + srow) * D_DIM + k0 + scol),
          (las_ptr)((char*)Bs + j * 4096 + wave * 1024), 16, 0, 0);
    }
    __syncthreads();
    s16x8 af[4], bf[4];
#pragma unroll
    for (int mi = 0; mi < 4; ++mi)
      af[mi] = *(const s16x8*)((const char*)As + (wm + mi * 16 + l15) * 64 + lhi * 16);
#pragma unroll
    for (int ni = 0; ni < 4; ++ni)
      bf[ni] = *(const s16x8*)((const char*)Bs + (wn + ni * 16 + l15) * 64 + lhi * 16);
#pragma unroll
    for (int mi = 0; mi < 4; ++mi)
#pragma unroll
      for (int ni = 0; ni < 4; ++ni)
        acc[mi][ni] = mfma_bf16(af[mi], bf[ni], acc[mi][ni]);
    __syncthreads();
  }

#pragma unroll
  for (int mi = 0; mi < 4; ++mi)
#pragma unroll
    for (int ni = 0; ni < 4; ++ni)
#pragma unroll
      for (int r = 0; r < 4; ++r) {
        int row = m0 + wm + mi * 16 + lhi * 4 + r;
        int col = n0 + wn + ni * 16 + l15;
        if (mode == 0) {
          int c = col & 1023;
          float bb = (col < 1024) ? bias0[c] * QK_SCALE : bias1[c];
          unsigned short* dst = (col < 1024) ? out0 : out1;
          unsigned short bv = f32_to_bf16(acc[mi][ni][r] + bb);
          int b = row >> 11, s = row & 2047;
          int h = c >> 6, d = c & 63;
          dst[((size_t)(b * NH + h) * S_LEN + s) * HD + d] = bv;
        } else {
          unsigned short bv = f32_to_bf16(acc[mi][ni][r] + bias0[row]);
          int h = row >> 6, d = row & 63;
          int b = col >> 11, s = col & 2047;
          out0[((size_t)(b * NH + h) * HD + d) * S_LEN + s] = bv;
        }
      }
}

// ---------------- flash attention: LDS-staged double-buffered K/V ----------------
// grid 1024 blocks. Mapping (perf-heuristic, bijective): xcd=idx&7, slot=idx>>3,
// bh=xcd*4+(slot>>5), qc=slot&31. A head's 32 blocks -> one XCD (L2-resident
// K/V, 4 heads x 1MB = 4MB/XCD); same-CU residency slots -> 4 different heads
// (gate load balance). 4 waves, 16 q-rows/wave, 64-key tiles.
// Scores arrive pre-scaled to base-2 (Wq folded); softmax uses raw v_exp_f32.
// Per tile: fire DMA for t+1, compute t, one barrier. K/V LDS XOR-swizzled via
// pre-swizzled global source. Defer-max (THR=11 in base-2 = e^8 bound).
__global__ __launch_bounds__(256) void attn_kernel(
    const unsigned short* __restrict__ Q, const unsigned short* __restrict__ K,
    const unsigned short* __restrict__ Vt, const float* __restrict__ mask,
    const float* __restrict__ gate, float* __restrict__ Out) {
  __shared__ __align__(16) unsigned short Ks[2][64 * 64];   // [key][d], swizzled
  __shared__ __align__(16) unsigned short Vs[2][64 * 64];   // [d][key], swizzled
  __shared__ __align__(16) unsigned short p_lds[4][16][72];

  int idx = blockIdx.x;
  int xcd = idx & 7;
  int slot = idx >> 3;
  int bh = xcd * 4 + (slot >> 5);
  int qc = slot & 31;
  int b = bh >> 4, h = bh & 15;
  int tid = threadIdx.x;
  int wave = tid >> 6, lane = tid & 63;
  int l15 = lane & 15, lhi = lane >> 4;
  int q0 = qc * 64 + wave * 16;
  int qrow = q0 + l15;

  float g = gate[bh];
  if (g == 0.f) {  // gated-off head: exactly zero (block-uniform exit, pre-barrier)
    float4 z = {0.f, 0.f, 0.f, 0.f};
#pragma unroll
    for (int dd = 0; dd < 4; ++dd)
      *(float4*)(Out + ((size_t)b * S_LEN + qrow) * D_DIM + h * HD + lhi * 16 + dd * 4) = z;
    return;
  }

  const unsigned short* Qp = Q + (size_t)bh * S_LEN * HD;
  const unsigned short* Kp = K + (size_t)bh * S_LEN * HD;
  const unsigned short* Vp = Vt + (size_t)bh * HD * S_LEN;
  const float* maskp = mask + (size_t)b * S_LEN;

  // staging geometry: per lane, two 16B DMA chunks covering this wave's 2KB slice
  int o0 = wave * 2048 + lane * 16;  // byte offset within the 8KB tile

#define STAGE(BUFI, KTV)                                                          \
  {                                                                               \
    _Pragma("unroll") for (int j = 0; j < 2; ++j) {                               \
      int oo = o0 + j * 1024;                                                     \
      int row = oo >> 7;                                                          \
      int e = ((oo & 127) ^ ((row & 7) << 4)) >> 1;                               \
      __builtin_amdgcn_global_load_lds(                                           \
          (gas_ptr)(Kp + (size_t)((KTV) + row) * HD + e),                         \
          (las_ptr)(&Ks[BUFI][(wave * 2048 + j * 1024) >> 1]), 16, 0, 0);         \
      __builtin_amdgcn_global_load_lds(                                           \
          (gas_ptr)(Vp + (size_t)row * S_LEN + (KTV) + e),                        \
          (las_ptr)(&Vs[BUFI][(wave * 2048 + j * 1024) >> 1]), 16, 0, 0);         \
    }                                                                             \
  }

  // prologue: stage tile 0 into buf 0; Q fragments -> regs
  STAGE(0, 0);
  s16x8 q_frag[2];
#pragma unroll
  for (int ks = 0; ks < 2; ++ks)
    q_frag[ks] = *(const s16x8*)(Qp + (size_t)qrow * HD + ks * 32 + lhi * 8);

  f32x4 o_acc[4] = {};
  float m_run = -1e30f, s_run = 0.f;

  __syncthreads();  // tile 0 staged & visible

  for (int kt = 0; kt < S_LEN; kt += 64) {
    int buf = (kt >> 6) & 1;
    int ktn = (kt + 64) & (S_LEN - 1);  // last iter wraps harmlessly
    STAGE(buf ^ 1, ktn);                // fire next-tile DMA before compute

    // mask slice (L2-hot, issued before MFMA phase -> latency hidden)
    float4 mv[4];
#pragma unroll
    for (int nf = 0; nf < 4; ++nf)
      mv[nf] = *(const float4*)(maskp + kt + nf * 16 + lhi * 4);

    // ---- QK^T from LDS (swizzled reads): sc[nf][r] = S[q=l15][key=nf*16+lhi*4+r]
    f32x4 sc[4] = {};
    __builtin_amdgcn_s_setprio(1);
#pragma unroll
    for (int ks = 0; ks < 2; ++ks)
#pragma unroll
      for (int nf = 0; nf < 4; ++nf) {
        int row = nf * 16 + l15;
        int ofs = (row * 128 + ks * 64 + lhi * 16) ^ ((row & 7) << 4);
        s16x8 af = *(const s16x8*)((const char*)&Ks[buf][0] + ofs);
        sc[nf] = mfma_bf16(af, q_frag[ks], sc[nf]);
      }
    __builtin_amdgcn_s_setprio(0);

    // ---- +mask (base-2 domain) + tree max (lane-local row stats)
    float mnf[4];
#pragma unroll
    for (int nf = 0; nf < 4; ++nf) {
#pragma unroll
      for (int r = 0; r < 4; ++r)
        sc[nf][r] = sc[nf][r] + ((const float*)&mv[nf])[r] * LOG2E;
      mnf[nf] = fmaxf(fmaxf(sc[nf][0], sc[nf][1]), fmaxf(sc[nf][2], sc[nf][3]));
    }
    float pmax = fmaxf(fmaxf(mnf[0], mnf[1]), fmaxf(mnf[2], mnf[3]));
    pmax = fmaxf(pmax, __shfl_xor(pmax, 16, 64));
    pmax = fmaxf(pmax, __shfl_xor(pmax, 32, 64));

    // defer-max: skip rescale while tile max stays within THR of running max
    if (!__all(pmax <= m_run + 11.f)) {
      float m_new = fmaxf(m_run, pmax);
      float corr = exp2_fast(m_run - m_new);
      m_run = m_new;
      s_run *= corr;
#pragma unroll
      for (int df = 0; df < 4; ++df)
#pragma unroll
        for (int r = 0; r < 4; ++r) o_acc[df][r] *= corr;
    }

    float psnf[4];
#pragma unroll
    for (int nf = 0; nf < 4; ++nf) {
#pragma unroll
      for (int r = 0; r < 4; ++r) sc[nf][r] = exp2_fast(sc[nf][r] - m_run);
      psnf[nf] = (sc[nf][0] + sc[nf][1]) + (sc[nf][2] + sc[nf][3]);
    }
    float ps = (psnf[0] + psnf[1]) + (psnf[2] + psnf[3]);
    ps += __shfl_xor(ps, 16, 64);
    ps += __shfl_xor(ps, 32, 64);
    s_run += ps;

    // ---- P -> per-wave LDS slice (barrier-ordered; re-layout for PV A-operand)
#pragma unroll
    for (int nf = 0; nf < 4; ++nf) {
      unsigned int lo = (unsigned int)f32_to_bf16(sc[nf][0]) |
                        ((unsigned int)f32_to_bf16(sc[nf][1]) << 16);
      unsigned int hi = (unsigned int)f32_to_bf16(sc[nf][2]) |
                        ((unsigned int)f32_to_bf16(sc[nf][3]) << 16);
      uint2 pk = {lo, hi};
      *(uint2*)&p_lds[wave][l15][nf * 16 + lhi * 4] = pk;
    }

    // ---- O^T += V^T · P^T from LDS (swizzled V reads)
    __builtin_amdgcn_s_setprio(1);
#pragma unroll
    for (int ks = 0; ks < 2; ++ks) {
      s16x8 pf = *(const s16x8*)&p_lds[wave][l15][ks * 32 + lhi * 8];
#pragma unroll
      for (int df = 0; df < 4; ++df) {
        int row = df * 16 + l15;
        int ofs = (row * 128 + ks * 64 + lhi * 16) ^ ((row & 7) << 4);
        s16x8 vf = *(const s16x8*)((const char*)&Vs[buf][0] + ofs);
        o_acc[df] = mfma_bf16(vf, pf, o_acc[df]);
      }
    }
    __builtin_amdgcn_s_setprio(0);

    __syncthreads();  // drains our DMA (vmcnt 0) + WAR fence on buf/p_lds
  }
#undef STAGE

  float inv = g / s_run;
#pragma unroll
  for (int df = 0; df < 4; ++df) {
    float4 ov;
    ov.x = o_acc[df][0] * inv;
    ov.y = o_acc[df][1] * inv;
    ov.z = o_acc[df][2] * inv;
    ov.w = o_acc[df][3] * inv;
    *(float4*)(Out + ((size_t)b * S_LEN + qrow) * D_DIM + h * HD + df * 16 + lhi * 4) = ov;
  }
}

// ---------------- launch ----------------

extern "C" void kernel_launch(void* const* d_in, const int* in_sizes, int n_in,
                              void* d_out, int out_size, void* d_ws, size_t ws_size,
                              hipStream_t stream) {
  (void)in_sizes; (void)n_in; (void)out_size; (void)ws_size;
  const float* hs   = (const float*)d_in[0];
  const float* mask = (const float*)d_in[1];
  const float* Wq   = (const float*)d_in[2];
  const float* bq   = (const float*)d_in[3];
  const float* Wk   = (const float*)d_in[4];
  const float* bk   = (const float*)d_in[5];
  const float* Wv   = (const float*)d_in[6];
  const float* bv   = (const float*)d_in[7];
  const float* pW1  = (const float*)d_in[8];
  const float* pb1  = (const float*)d_in[9];
  const float* gam  = (const float*)d_in[10];
  const float* bet  = (const float*)d_in[11];
  const float* mea  = (const float*)d_in[12];
  const float* var  = (const float*)d_in[13];
  const float* pW2  = (const float*)d_in[14];
  const float* pb2  = (const float*)d_in[15];
  float* out = (float*)d_out;

  const size_t MB = 1u << 20;
  char* ws = (char*)d_ws;
  unsigned short* hsb = (unsigned short*)(ws);            // 8 MB [4096][1024]
  unsigned short* wTq = (unsigned short*)(ws + 8 * MB);   // 2 MB (wTk must follow!)
  unsigned short* wTk = (unsigned short*)(ws + 10 * MB);  // 2 MB
  unsigned short* wTv = (unsigned short*)(ws + 12 * MB);  // 2 MB
  unsigned short* Qb  = (unsigned short*)(ws + 14 * MB);  // 8 MB [32][2048][64]
  unsigned short* Kb  = (unsigned short*)(ws + 22 * MB);  // 8 MB [32][2048][64]
  unsigned short* Vtb = (unsigned short*)(ws + 30 * MB);  // 8 MB [32][64][2048]
  float* partial = (float*)(ws + 38 * MB);                // 64 KB [2][8][1024]
  float* gateb   = (float*)(ws + 38 * MB + 65536);        // 128 B [32]

  cvt_hs_bf16<<<2048, 256, 0, stream>>>(hs, hsb);
  transpose_w<<<dim3(32, 32), 256, 0, stream>>>(Wq, wTq, QK_SCALE);
  transpose_w<<<dim3(32, 32), 256, 0, stream>>>(Wk, wTk, 1.0f);
  transpose_w<<<dim3(32, 32), 256, 0, stream>>>(Wv, wTv, 1.0f);
  pool_partial<<<64, 256, 0, stream>>>(hs, partial);
  gate_kernel<<<1, 256, 0, stream>>>(partial, pW1, pb1, gam, bet, mea, var, pW2, pb2, gateb);

  // fused Q+K projection: N = 2048 over [wTq | wTk] (adjacent in ws)
  proj_gemm2<<<dim3(32, 16), 256, 0, stream>>>(hsb, wTq, bq, bk, Qb, Kb, 0);
  // V^T projection
  proj_gemm2<<<dim3(8, 32), 256, 0, stream>>>(wTv, hsb, bv, nullptr, Vtb, nullptr, 1);

  attn_kernel<<<1024, 256, 0, stream>>>(Qb, Kb, Vtb, mask, gateb, out);
}

// Round 7
// 159.272 us; speedup vs baseline: 1.1109x; 1.1109x over previous
//
#include <hip/hip_runtime.h>

#define S_LEN 2048
#define D_DIM 1024
#define NH 16
#define HD 64
#define BATCH 2

// 0.125 (1/sqrt(hd)) * log2(e): folded into Wq/bq so QK^T scores are base-2
#define QK_SCALE 0.18033688011112042f
#define LOG2E 1.4426950408889634f

using s16x8 = __attribute__((ext_vector_type(8))) short;
using u16x8 = __attribute__((ext_vector_type(8))) unsigned short;
using f32x4 = __attribute__((ext_vector_type(4))) float;
using bf16x8v = __attribute__((ext_vector_type(8))) __bf16;

typedef const __attribute__((address_space(1))) unsigned int* gas_ptr;
typedef __attribute__((address_space(3))) unsigned int* las_ptr;

__device__ __forceinline__ unsigned short f32_to_bf16(float f) {
  unsigned int u = __float_as_uint(f);
  u += 0x7FFFu + ((u >> 16) & 1u);
  return (unsigned short)(u >> 16);
}

__device__ __forceinline__ f32x4 mfma_bf16(s16x8 a, s16x8 b, f32x4 c) {
  return __builtin_amdgcn_mfma_f32_16x16x32_bf16(
      __builtin_bit_cast(bf16x8v, a), __builtin_bit_cast(bf16x8v, b), c, 0, 0, 0);
}

// v_exp_f32 computes 2^x natively (ISA §3)
__device__ __forceinline__ float exp2_fast(float x) {
  float r;
  asm("v_exp_f32 %0, %1" : "=v"(r) : "v"(x));
  return r;
}

// ---------------- conversion kernels ----------------

__global__ __launch_bounds__(256) void cvt_hs_bf16(const float* __restrict__ in,
                                                   unsigned short* __restrict__ out) {
  int i = (blockIdx.x * 256 + threadIdx.x) * 8;
  float4 v0 = *(const float4*)(in + i);
  float4 v1 = *(const float4*)(in + i + 4);
  u16x8 o;
  o[0] = f32_to_bf16(v0.x); o[1] = f32_to_bf16(v0.y);
  o[2] = f32_to_bf16(v0.z); o[3] = f32_to_bf16(v0.w);
  o[4] = f32_to_bf16(v1.x); o[5] = f32_to_bf16(v1.y);
  o[6] = f32_to_bf16(v1.z); o[7] = f32_to_bf16(v1.w);
  *(u16x8*)(out + i) = o;
}

// WT[n][k] = W[k][n] * scale, f32 -> bf16; grid.z selects {Wq,Wk,Wv}
__global__ __launch_bounds__(256) void transpose_w3(
    const float* __restrict__ Wq, const float* __restrict__ Wk,
    const float* __restrict__ Wv, unsigned short* __restrict__ WTq,
    unsigned short* __restrict__ WTk, unsigned short* __restrict__ WTv) {
  __shared__ float tile[32][33];
  int z = blockIdx.z;
  const float* W = (z == 0) ? Wq : (z == 1) ? Wk : Wv;
  unsigned short* WT = (z == 0) ? WTq : (z == 1) ? WTk : WTv;
  float scale = (z == 0) ? QK_SCALE : 1.0f;
  int tx = threadIdx.x & 31;
  int ty = threadIdx.x >> 5;  // 0..7
  int c0 = blockIdx.x * 32;   // n range
  int r0 = blockIdx.y * 32;   // k range
#pragma unroll
  for (int i = 0; i < 4; ++i)
    tile[ty + i * 8][tx] = W[(r0 + ty + i * 8) * D_DIM + c0 + tx];
  __syncthreads();
#pragma unroll
  for (int i = 0; i < 4; ++i)
    WT[(c0 + ty + i * 8) * D_DIM + r0 + tx] = f32_to_bf16(tile[tx][ty + i * 8] * scale);
}

// ---------------- pooling + gate ----------------

__global__ __launch_bounds__(256) void pool_partial(const float* __restrict__ hs,
                                                    float* __restrict__ partial) {
  int bid = blockIdx.x;  // 64 = 2 * 8 * 4
  int b = bid & 1;
  int chunk = (bid >> 1) & 7;
  int dq = bid >> 4;  // 0..3
  int d = dq * 256 + threadIdx.x;
  const float* p = hs + ((size_t)b * S_LEN + chunk * 256) * D_DIM + d;
  float s = 0.f;
  for (int i = 0; i < 256; ++i) s += p[(size_t)i * D_DIM];
  partial[(b * 8 + chunk) * D_DIM + d] = s;
}

__global__ __launch_bounds__(256) void gate_kernel(
    const float* __restrict__ partial, const float* __restrict__ pW1,
    const float* __restrict__ pb1, const float* __restrict__ gamma,
    const float* __restrict__ beta, const float* __restrict__ mean,
    const float* __restrict__ var, const float* __restrict__ pW2,
    const float* __restrict__ pb2, float* __restrict__ gate) {
  __shared__ float pooled[2 * D_DIM];
  __shared__ float hsh[2][64];
  int t = threadIdx.x;
  for (int idx = t; idx < 2 * D_DIM; idx += 256) {
    int b = idx >> 10, k = idx & 1023;
    float s = 0.f;
#pragma unroll
    for (int c = 0; c < 8; ++c) s += partial[(b * 8 + c) * D_DIM + k];
    pooled[idx] = s * (1.0f / 2048.0f);
  }
  __syncthreads();
  // 2 threads per (b,j): split k-range, shfl combine
  int b = t >> 7, jj = (t >> 1) & 63, half = t & 1;
  float acc = 0.f;
  for (int k = half * 512; k < half * 512 + 512; ++k)
    acc += pooled[b * D_DIM + k] * pW1[k * 64 + jj];
  acc += __shfl_xor(acc, 1, 64);
  if (half == 0) {
    acc += pb1[jj];
    acc = (acc - mean[jj]) * rsqrtf(var[jj] + 1e-12f) * gamma[jj] + beta[jj];
    hsh[b][jj] = fmaxf(acc, 0.f);
  }
  __syncthreads();
  if (t < 32) {
    int bb = t >> 4, hh = t & 15;
    float lg = pb2[hh];
#pragma unroll
    for (int kk = 0; kk < 64; ++kk) lg += hsh[bb][kk] * pW2[kk * NH + hh];
    gate[bb * NH + hh] = (lg >= 0.f) ? 1.f : 0.f;
  }
}

// ---------------- fused QKV projection GEMM --------------------------------------
// C[4096][3072] = hsb[4096][1024] x BT[3072][1024] (BT = wTq|wTk|wTv contiguous).
// 128x128 tile, BK=32, 4 waves (2x2 of 64x64), global_load_lds 16B staging.
// Epilogue per 1024-col segment: 0->Q [b,h,s,d], 1->K [b,h,s,d], 2->V^T [b,h,d,s].
// Grid 768 flat, m-striped XCD swizzle: xcd gets a contiguous 4-row m-stripe.
__global__ __launch_bounds__(256) void proj_gemm3(
    const unsigned short* __restrict__ A, const unsigned short* __restrict__ BT,
    const float* __restrict__ bq, const float* __restrict__ bk,
    const float* __restrict__ bv, unsigned short* __restrict__ Qb,
    unsigned short* __restrict__ Kb, unsigned short* __restrict__ Vtb) {
  __shared__ __align__(16) unsigned short As[128 * 32];
  __shared__ __align__(16) unsigned short Bs[128 * 32];
  int idx = blockIdx.x;            // 0..767
  int xcd = idx & 7, j = idx >> 3; // j 0..95
  int xm = xcd * 4 + j / 24;       // m-tile 0..31 (4 per XCD)
  int yn = j % 24;                 // n-tile 0..23
  int m0 = xm * 128, n0 = yn * 128;
  int tid = threadIdx.x, wave = tid >> 6, lane = tid & 63;
  int l15 = lane & 15, lhi = lane >> 4;
  int wm = (wave >> 1) * 64, wn = (wave & 1) * 64;
  int srow = tid >> 2;        // 0..63
  int scol = (tid & 3) * 8;   // 0/8/16/24
  f32x4 acc[4][4] = {};

  for (int k0 = 0; k0 < D_DIM; k0 += 32) {
#pragma unroll
    for (int jj = 0; jj < 2; ++jj) {
      __builtin_amdgcn_global_load_lds(
          (gas_ptr)(A + (size_t)(m0 + jj * 64 + srow) * D_DIM + k0 + scol),
          (las_ptr)((char*)As + jj * 4096 + wave * 1024), 16, 0, 0);
      __builtin_amdgcn_global_load_lds(
          (gas_ptr)(BT + (size_t)(n0 + jj * 64 + srow) * D_DIM + k0 + scol),
          (las_ptr)((char*)Bs + jj * 4096 + wave * 1024), 16, 0, 0);
    }
    __syncthreads();
    s16x8 af[4], bf[4];
#pragma unroll
    for (int mi = 0; mi < 4; ++mi)
      af[mi] = *(const s16x8*)((const char*)As + (wm + mi * 16 + l15) * 64 + lhi * 16);
#pragma unroll
    for (int ni = 0; ni < 4; ++ni)
      bf[ni] = *(const s16x8*)((const char*)Bs + (wn + ni * 16 + l15) * 64 + lhi * 16);
#pragma unroll
    for (int mi = 0; mi < 4; ++mi)
#pragma unroll
      for (int ni = 0; ni < 4; ++ni)
        acc[mi][ni] = mfma_bf16(af[mi], bf[ni], acc[mi][ni]);
    __syncthreads();
  }

#pragma unroll
  for (int mi = 0; mi < 4; ++mi)
#pragma unroll
    for (int ni = 0; ni < 4; ++ni) {
      int row0 = m0 + wm + mi * 16 + lhi * 4;
      int col = n0 + wn + ni * 16 + l15;
      int seg = col >> 10, c = col & 1023;
      if (seg == 2) {
        // V: 4 consecutive s values -> one packed 8B store to [b,h,d,s]
        float bvv = bv[c];
        int h = c >> 6, d = c & 63;
        int b = row0 >> 11, s = row0 & 2047;
        ushort4 pk;
        pk.x = f32_to_bf16(acc[mi][ni][0] + bvv);
        pk.y = f32_to_bf16(acc[mi][ni][1] + bvv);
        pk.z = f32_to_bf16(acc[mi][ni][2] + bvv);
        pk.w = f32_to_bf16(acc[mi][ni][3] + bvv);
        *(ushort4*)&Vtb[((size_t)(b * NH + h) * HD + d) * S_LEN + s] = pk;
      } else {
        float bb = (seg == 0) ? bq[c] * QK_SCALE : bk[c];
        unsigned short* dst = (seg == 0) ? Qb : Kb;
        int h = c >> 6, d = c & 63;
#pragma unroll
        for (int r = 0; r < 4; ++r) {
          int row = row0 + r;
          int b = row >> 11, s = row & 2047;
          dst[((size_t)(b * NH + h) * S_LEN + s) * HD + d] =
              f32_to_bf16(acc[mi][ni][r] + bb);
        }
      }
    }
}

// ---------------- flash attention: gate-aware remap + LDS dbuf K/V ---------------
// grid 1024. xcd=idx&7, s=idx>>3, qc=s&31, rank r=(s>>5)*8+xcd in [0,32).
// Every block ballots the 32-entry gate: W = #live heads. r<W -> process the r-th
// LIVE head (its 32 q-blocks all have idx&7==r&7 -> one XCD: K/V L2-local AND
// load-balanced ±1 rank/XCD). r>=W -> zero-fill the (r-W)-th gated head.
// 4 waves, 16 q-rows/wave, 64-key tiles, base-2 softmax (Wq pre-scaled),
// defer-max THR=11. LDS = exactly 40960 B -> 4 blocks/CU. All LDS XOR-swizzled
// (byte ^= (l15&7)<<4) via pre-swizzled global source for the DMA'd K/V.
__global__ __launch_bounds__(256) void attn_kernel(
    const unsigned short* __restrict__ Q, const unsigned short* __restrict__ K,
    const unsigned short* __restrict__ Vt, const float* __restrict__ mask,
    const float* __restrict__ gate, float* __restrict__ Out) {
  __shared__ __align__(16) unsigned short Ks[2][4096];   // [key][d], swizzled
  __shared__ __align__(16) unsigned short Vs[2][4096];   // [d][key], swizzled
  __shared__ __align__(16) unsigned short p_lds[4][1024];  // [q][key], swizzled

  int idx = blockIdx.x;
  int xcd = idx & 7;
  int slot = idx >> 3;
  int qc = slot & 31;
  int r = (slot >> 5) * 8 + xcd;  // rank 0..31
  int tid = threadIdx.x;
  int wave = tid >> 6, lane = tid & 63;
  int l15 = lane & 15, lhi = lane >> 4;

  // ballot the gate vector (uniform across waves)
  float gv = (lane < 32) ? gate[lane] : 0.f;
  unsigned long long live = __ballot(gv != 0.f);
  int W = __popcll(live);
  bool working = (r < W);
  int want = working ? r : (r - W);
  unsigned long long M = working ? live : (~live & 0xFFFFFFFFull);
  int head = 0, c = 0;
#pragma unroll
  for (int hh = 0; hh < 32; ++hh) {
    if ((M >> hh) & 1) {
      if (c == want) head = hh;
      ++c;
    }
  }
  int b = head >> 4, h = head & 15;
  int q0 = qc * 64 + wave * 16;
  int qrow = q0 + l15;

  if (!working) {
    // zero-fill this gated head's 64-row slice: 64 rows x 64 cols f32
    float4 z = {0.f, 0.f, 0.f, 0.f};
    int row = qc * 64 + (tid >> 2);
    float* op = Out + ((size_t)b * S_LEN + row) * D_DIM + h * HD + (tid & 3) * 16;
#pragma unroll
    for (int dd = 0; dd < 4; ++dd) *(float4*)(op + dd * 4) = z;
    return;
  }

  const unsigned short* Qp = Q + (size_t)head * S_LEN * HD;
  const unsigned short* Kp = K + (size_t)head * S_LEN * HD;
  const unsigned short* Vp = Vt + (size_t)head * HD * S_LEN;
  const float* maskp = mask + (size_t)b * S_LEN;

  // hoisted staging addresses: lane covers two 16B chunks of the 8KB tile
  int psw = (l15 & 7) << 4;
  int oo0 = wave * 2048 + lane * 16;
  int oo1 = oo0 + 1024;
  int row0 = oo0 >> 7, row1 = oo1 >> 7;
  int e0 = ((oo0 & 127) ^ ((row0 & 7) << 4)) >> 1;
  int e1 = ((oo1 & 127) ^ ((row1 & 7) << 4)) >> 1;
  const unsigned short* kb0 = Kp + row0 * HD + e0;
  const unsigned short* kb1 = Kp + row1 * HD + e1;
  const unsigned short* vb0 = Vp + (size_t)row0 * S_LEN + e0;
  const unsigned short* vb1 = Vp + (size_t)row1 * S_LEN + e1;
  unsigned short* ksb = &Ks[0][0];
  unsigned short* vsb = &Vs[0][0];
  int w0 = (wave * 2048) >> 1;  // LDS short-index of this wave's slice
  int w1 = w0 + 512;

#define STAGE(BUFI, KTV)                                                            \
  {                                                                                 \
    __builtin_amdgcn_global_load_lds((gas_ptr)(kb0 + (size_t)(KTV) * HD),           \
                                     (las_ptr)(ksb + (BUFI) * 4096 + w0), 16, 0, 0);\
    __builtin_amdgcn_global_load_lds((gas_ptr)(kb1 + (size_t)(KTV) * HD),           \
                                     (las_ptr)(ksb + (BUFI) * 4096 + w1), 16, 0, 0);\
    __builtin_amdgcn_global_load_lds((gas_ptr)(vb0 + (KTV)),                        \
                                     (las_ptr)(vsb + (BUFI) * 4096 + w0), 16, 0, 0);\
    __builtin_amdgcn_global_load_lds((gas_ptr)(vb1 + (KTV)),                        \
                                     (las_ptr)(vsb + (BUFI) * 4096 + w1), 16, 0, 0);\
  }

  STAGE(0, 0);
  s16x8 q_frag[2];
#pragma unroll
  for (int ks = 0; ks < 2; ++ks)
    q_frag[ks] = *(const s16x8*)(Qp + (size_t)qrow * HD + ks * 32 + lhi * 8);

  // loop-invariant swizzled column offsets
  int swz0 = (lhi * 16) ^ psw;        // ks=0
  int swz1 = (64 + lhi * 16) ^ psw;   // ks=1
  char* pbase = (char*)p_lds + wave * 2048 + l15 * 128;

  f32x4 o_acc[4] = {};
  float m_run = -1e30f, s_run = 0.f;

  __syncthreads();  // tile 0 staged & visible

  for (int kt = 0; kt < S_LEN; kt += 64) {
    int buf = (kt >> 6) & 1;
    int ktn = (kt + 64) & (S_LEN - 1);  // last iter wraps harmlessly
    STAGE(buf ^ 1, ktn);                // fire next-tile DMA before compute

    // mask slice (L2-hot, issued before MFMA phase)
    float4 mv[4];
#pragma unroll
    for (int nf = 0; nf < 4; ++nf)
      mv[nf] = *(const float4*)(maskp + kt + nf * 16 + lhi * 4);

    // ---- QK^T from LDS: sc[nf][r] = S[q=l15][key=nf*16+lhi*4+r]
    const char* kc = (const char*)ksb + buf * 8192;
    f32x4 sc[4] = {};
    __builtin_amdgcn_s_setprio(1);
#pragma unroll
    for (int nf = 0; nf < 4; ++nf) {
      int rb = (nf * 16 + l15) * 128;
      s16x8 a0 = *(const s16x8*)(kc + (rb + swz0));
      s16x8 a1 = *(const s16x8*)(kc + (rb + swz1));
      sc[nf] = mfma_bf16(a0, q_frag[0], sc[nf]);
      sc[nf] = mfma_bf16(a1, q_frag[1], sc[nf]);
    }
    __builtin_amdgcn_s_setprio(0);

    // ---- +mask (base-2) + tree max (lane-local row stats)
    float mnf[4];
#pragma unroll
    for (int nf = 0; nf < 4; ++nf) {
#pragma unroll
      for (int rr = 0; rr < 4; ++rr)
        sc[nf][rr] = sc[nf][rr] + ((const float*)&mv[nf])[rr] * LOG2E;
      mnf[nf] = fmaxf(fmaxf(sc[nf][0], sc[nf][1]), fmaxf(sc[nf][2], sc[nf][3]));
    }
    float pmax = fmaxf(fmaxf(mnf[0], mnf[1]), fmaxf(mnf[2], mnf[3]));
    pmax = fmaxf(pmax, __shfl_xor(pmax, 16, 64));
    pmax = fmaxf(pmax, __shfl_xor(pmax, 32, 64));

    // defer-max: skip rescale while tile max stays within THR of running max
    if (!__all(pmax <= m_run + 11.f)) {
      float m_new = fmaxf(m_run, pmax);
      float corr = exp2_fast(m_run - m_new);
      m_run = m_new;
      s_run *= corr;
#pragma unroll
      for (int df = 0; df < 4; ++df)
#pragma unroll
        for (int rr = 0; rr < 4; ++rr) o_acc[df][rr] *= corr;
    }

    float psnf[4];
#pragma unroll
    for (int nf = 0; nf < 4; ++nf) {
#pragma unroll
      for (int rr = 0; rr < 4; ++rr) sc[nf][rr] = exp2_fast(sc[nf][rr] - m_run);
      psnf[nf] = (sc[nf][0] + sc[nf][1]) + (sc[nf][2] + sc[nf][3]);
    }
    float ps = (psnf[0] + psnf[1]) + (psnf[2] + psnf[3]);
    ps += __shfl_xor(ps, 16, 64);
    ps += __shfl_xor(ps, 32, 64);
    s_run += ps;

    // ---- P -> per-wave LDS slice (swizzled; barrier-ordered WAR)
#pragma unroll
    for (int nf = 0; nf < 4; ++nf) {
      unsigned int lo = (unsigned int)f32_to_bf16(sc[nf][0]) |
                        ((unsigned int)f32_to_bf16(sc[nf][1]) << 16);
      unsigned int hi = (unsigned int)f32_to_bf16(sc[nf][2]) |
                        ((unsigned int)f32_to_bf16(sc[nf][3]) << 16);
      uint2 pk = {lo, hi};
      *(uint2*)(pbase + ((nf * 32 + lhi * 8) ^ psw)) = pk;
    }

    // ---- O^T += V^T · P^T from LDS (swizzled reads)
    const char* vc = (const char*)vsb + buf * 8192;
    __builtin_amdgcn_s_setprio(1);
#pragma unroll
    for (int ks = 0; ks < 2; ++ks) {
      int sw = ks ? swz1 : swz0;
      s16x8 pf = *(const s16x8*)(pbase + ((ks * 64 + lhi * 16) ^ psw));
#pragma unroll
      for (int df = 0; df < 4; ++df) {
        s16x8 vf = *(const s16x8*)(vc + ((df * 16 + l15) * 128 + sw));
        o_acc[df] = mfma_bf16(vf, pf, o_acc[df]);
      }
    }
    __builtin_amdgcn_s_setprio(0);

    __syncthreads();  // drains our DMA (vmcnt 0) + WAR fence on buf/p_lds
  }
#undef STAGE

  float inv = 1.0f / s_run;
#pragma unroll
  for (int df = 0; df < 4; ++df) {
    float4 ov;
    ov.x = o_acc[df][0] * inv;
    ov.y = o_acc[df][1] * inv;
    ov.z = o_acc[df][2] * inv;
    ov.w = o_acc[df][3] * inv;
    *(float4*)(Out + ((size_t)b * S_LEN + qrow) * D_DIM + h * HD + df * 16 + lhi * 4) = ov;
  }
}

// ---------------- launch ----------------

extern "C" void kernel_launch(void* const* d_in, const int* in_sizes, int n_in,
                              void* d_out, int out_size, void* d_ws, size_t ws_size,
                              hipStream_t stream) {
  (void)in_sizes; (void)n_in; (void)out_size; (void)ws_size;
  const float* hs   = (const float*)d_in[0];
  const float* mask = (const float*)d_in[1];
  const float* Wq   = (const float*)d_in[2];
  const float* bq   = (const float*)d_in[3];
  const float* Wk   = (const float*)d_in[4];
  const float* bk   = (const float*)d_in[5];
  const float* Wv   = (const float*)d_in[6];
  const float* bv   = (const float*)d_in[7];
  const float* pW1  = (const float*)d_in[8];
  const float* pb1  = (const float*)d_in[9];
  const float* gam  = (const float*)d_in[10];
  const float* bet  = (const float*)d_in[11];
  const float* mea  = (const float*)d_in[12];
  const float* var  = (const float*)d_in[13];
  const float* pW2  = (const float*)d_in[14];
  const float* pb2  = (const float*)d_in[15];
  float* out = (float*)d_out;

  const size_t MB = 1u << 20;
  char* ws = (char*)d_ws;
  unsigned short* hsb = (unsigned short*)(ws);            // 8 MB [4096][1024]
  unsigned short* wTq = (unsigned short*)(ws + 8 * MB);   // 2 MB  (wTq|wTk|wTv
  unsigned short* wTk = (unsigned short*)(ws + 10 * MB);  // 2 MB   must stay
  unsigned short* wTv = (unsigned short*)(ws + 12 * MB);  // 2 MB   contiguous!)
  unsigned short* Qb  = (unsigned short*)(ws + 14 * MB);  // 8 MB [32][2048][64]
  unsigned short* Kb  = (unsigned short*)(ws + 22 * MB);  // 8 MB [32][2048][64]
  unsigned short* Vtb = (unsigned short*)(ws + 30 * MB);  // 8 MB [32][64][2048]
  float* partial = (float*)(ws + 38 * MB);                // 64 KB [2][8][1024]
  float* gateb   = (float*)(ws + 38 * MB + 65536);        // 128 B [32]

  cvt_hs_bf16<<<2048, 256, 0, stream>>>(hs, hsb);
  transpose_w3<<<dim3(32, 32, 3), 256, 0, stream>>>(Wq, Wk, Wv, wTq, wTk, wTv);
  pool_partial<<<64, 256, 0, stream>>>(hs, partial);
  gate_kernel<<<1, 256, 0, stream>>>(partial, pW1, pb1, gam, bet, mea, var, pW2, pb2, gateb);

  // fused Q+K+V projection: N = 3072 over [wTq|wTk|wTv]
  proj_gemm3<<<768, 256, 0, stream>>>(hsb, wTq, bq, bk, bv, Qb, Kb, Vtb);

  attn_kernel<<<1024, 256, 0, stream>>>(Qb, Kb, Vtb, mask, gateb, out);
}